// Round 1
// baseline (1197.193 us; speedup 1.0000x reference)
//
#include <hip/hip_runtime.h>

// Problem: x (32,512,512) fp32 -> pad 128 each side -> (32,768,768)
//          -> nearest-neighbor x4 upsample -> out (32,3072,3072) fp32.
//
// Interior of output (nonzero) is rows/cols [512, 2560). Every aligned
// float4 of an output row is either all-zero padding or a 4-wide broadcast
// of one input element. Additionally, output rows come in groups of 4
// identical rows (nearest-neighbor x4 in the row dim):
//   rows 4g..4g+3 all equal the padded input row (g-128), g in [128,640).
//
// This version: ONE block per (row-group g, batch b). The block loads its
// input row once (3 regs/thread; quad-cols [256,512) are always interior,
// so only the two edge thirds need a bound check) and then issues
// 4 rows x 3 = 12 independent 16B non-temporal stores per thread.
// vs previous kernel (block per output row): 4x less input fetch (no
// cross-XCD re-read of the same input row), 4x fewer blocks, and 12
// dependency-free stores/thread instead of 3 load-dependent ones.

typedef float vfloat4 __attribute__((ext_vector_type(4)));

constexpr int OUTW = 3072;   // output width = height
constexpr int OUTQ = 768;    // float4 quads per output row
constexpr int IN   = 512;
constexpr int Q_LO = 128;    // first interior quad-col (512/4)
constexpr int G_LO = 128;    // first interior row-group (512/4)
constexpr int G_HI = 640;    // one-past-last interior row-group (2560/4)

__global__ __launch_bounds__(256) void scale_layer_kernel(
    const float* __restrict__ x, float* __restrict__ out) {
    const int g = blockIdx.x;          // row-group, 0..767 (output rows 4g..4g+3)
    const int b = blockIdx.y;          // batch, 0..31
    const int t = (int)threadIdx.x;    // 0..255

    vfloat4* obase = reinterpret_cast<vfloat4*>(out) +
                     ((size_t)b * OUTW + 4 * (size_t)g) * OUTQ;

    const bool in_row = (g >= G_LO) && (g < G_HI);
    // Only dereferenced when in_row.
    const float* irow = x + ((size_t)b * IN + (size_t)(g - G_LO)) * IN;

    // Quad-columns handled by this thread: t, t+256, t+512.
    //   t+256 in [256,512)  -> always interior (for interior rows)
    //   t     interior iff t >= 128
    //   t+512 interior iff t < 128
    float v0 = 0.0f, v1 = 0.0f, v2 = 0.0f;
    if (in_row) {
        if (t >= 128) v0 = irow[t - Q_LO];         // cols [0,128)   of input
        v1 = irow[t + 256 - Q_LO];                 // cols [128,384)
        if (t < 128)  v2 = irow[t + 512 - Q_LO];   // cols [384,512)
    }
    const vfloat4 w0 = {v0, v0, v0, v0};
    const vfloat4 w1 = {v1, v1, v1, v1};
    const vfloat4 w2 = {v2, v2, v2, v2};

    #pragma unroll
    for (int s = 0; s < 4; ++s) {                  // 4 identical output rows
        vfloat4* orow = obase + (size_t)s * OUTQ;
        __builtin_nontemporal_store(w0, &orow[t]);
        __builtin_nontemporal_store(w1, &orow[t + 256]);
        __builtin_nontemporal_store(w2, &orow[t + 512]);
    }
}

extern "C" void kernel_launch(void* const* d_in, const int* in_sizes, int n_in,
                              void* d_out, int out_size, void* d_ws, size_t ws_size,
                              hipStream_t stream) {
    const float* x = (const float*)d_in[0];
    float* out = (float*)d_out;
    dim3 grid(OUTQ, 32);   // one block per 4-row group per batch sample
    scale_layer_kernel<<<grid, 256, 0, stream>>>(x, out);
}

// Round 2
// 1193.847 us; speedup vs baseline: 1.0028x; 1.0028x over previous
//
#include <hip/hip_runtime.h>

// Problem: x (32,512,512) fp32 -> pad 128 each side -> (32,768,768)
//          -> nearest-neighbor x4 upsample -> out (32,3072,3072) fp32.
//
// Round 2: IDENTICAL structure to Round 1 (one block per 4-row output group,
// input row loaded once into 3 regs, 12 independent 16B stores/thread).
// Single variable changed: plain cached stores instead of
// __builtin_nontemporal_store. Rationale: rocclr fillBuffer sustains
// 6.23 TB/s on this same buffer with plain stores, while both NT-store
// kernel variants sit at ~3 TB/s effective; NT (MTYPE/stream path) is the
// only shared feature left to indict. Every 64B line is fully written
// exactly once, so L2 pollution from cached stores costs nothing.

typedef float vfloat4 __attribute__((ext_vector_type(4)));

constexpr int OUTW = 3072;   // output width = height
constexpr int OUTQ = 768;    // float4 quads per output row
constexpr int IN   = 512;
constexpr int Q_LO = 128;    // first interior quad-col (512/4)
constexpr int G_LO = 128;    // first interior row-group (512/4)
constexpr int G_HI = 640;    // one-past-last interior row-group (2560/4)

__global__ __launch_bounds__(256) void scale_layer_kernel(
    const float* __restrict__ x, float* __restrict__ out) {
    const int g = blockIdx.x;          // row-group, 0..767 (output rows 4g..4g+3)
    const int b = blockIdx.y;          // batch, 0..31
    const int t = (int)threadIdx.x;    // 0..255

    vfloat4* obase = reinterpret_cast<vfloat4*>(out) +
                     ((size_t)b * OUTW + 4 * (size_t)g) * OUTQ;

    const bool in_row = (g >= G_LO) && (g < G_HI);
    // Only dereferenced when in_row.
    const float* irow = x + ((size_t)b * IN + (size_t)(g - G_LO)) * IN;

    // Quad-columns handled by this thread: t, t+256, t+512.
    //   t+256 in [256,512)  -> always interior (for interior rows)
    //   t     interior iff t >= 128
    //   t+512 interior iff t < 128
    float v0 = 0.0f, v1 = 0.0f, v2 = 0.0f;
    if (in_row) {
        if (t >= 128) v0 = irow[t - Q_LO];         // cols [0,128)   of input
        v1 = irow[t + 256 - Q_LO];                 // cols [128,384)
        if (t < 128)  v2 = irow[t + 512 - Q_LO];   // cols [384,512)
    }
    const vfloat4 w0 = {v0, v0, v0, v0};
    const vfloat4 w1 = {v1, v1, v1, v1};
    const vfloat4 w2 = {v2, v2, v2, v2};

    #pragma unroll
    for (int s = 0; s < 4; ++s) {                  // 4 identical output rows
        vfloat4* orow = obase + (size_t)s * OUTQ;
        orow[t]       = w0;                        // plain cached stores
        orow[t + 256] = w1;
        orow[t + 512] = w2;
    }
}

extern "C" void kernel_launch(void* const* d_in, const int* in_sizes, int n_in,
                              void* d_out, int out_size, void* d_ws, size_t ws_size,
                              hipStream_t stream) {
    const float* x = (const float*)d_in[0];
    float* out = (float*)d_out;
    dim3 grid(OUTQ, 32);   // one block per 4-row group per batch sample
    scale_layer_kernel<<<grid, 256, 0, stream>>>(x, out);
}